// Round 8
// baseline (381.990 us; speedup 1.0000x reference)
//
#include <hip/hip_runtime.h>

typedef unsigned short ushort_t;
typedef __attribute__((ext_vector_type(8))) short short8;
typedef __attribute__((ext_vector_type(4))) float f32x4;
typedef __attribute__((ext_vector_type(4))) int int4v;

#define RNUM 8
#define FDIM 128

__device__ __forceinline__ float bf2f(ushort_t u) {
    union { unsigned int i; float f; } x;
    x.i = ((unsigned int)u) << 16;
    return x.f;
}
__device__ __forceinline__ ushort_t f2bf(float f) {
    union { float f; unsigned int i; } x;
    x.f = f;
    unsigned int u = x.i;
    u += 0x7fffu + ((u >> 16) & 1u);   // round-to-nearest-even
    return (ushort_t)(u >> 16);
}

// async global->LDS, 16B per lane; LDS dest is wave-uniform base + lane*16
__device__ __forceinline__ void gl_lds16(const void* g, void* s) {
    __builtin_amdgcn_global_load_lds(
        (const __attribute__((address_space(1))) unsigned int*)g,
        (__attribute__((address_space(3))) unsigned int*)s, 16, 0, 0);
}

// ---------------- per-NODE linked list + (node,rel) histogram ----------------
// head[node] (memset -1) -> most recent edge; nxt2[i] = {src, et<<20|prev}.
// prev sentinel = 0xFFFFF (E < 1M fits 20 bits, et fits 3 bits).

__global__ void link_hist(const int* __restrict__ src, const int* __restrict__ dst,
                          const int* __restrict__ et, int* head, int* cnt,
                          int2* __restrict__ nxt2, int E) {
    int i = blockIdx.x * 256 + threadIdx.x;
    if (i < E) {
        int d = dst[i], r = et[i];
        atomicAdd(&cnt[d * RNUM + r], 1);
        int old = atomicExch(&head[d], i);
        int nx = (old < 0) ? 0xFFFFF : old;
        nxt2[i] = make_int2(src[i], (r << 20) | nx);
    }
}

__global__ void inv_cnt(const int* __restrict__ cnt, float* __restrict__ invc, int n) {
    int i = blockIdx.x * 256 + threadIdx.x;
    if (i < n) {
        int c = cnt[i];
        invc[i] = c ? 1.0f / (float)c : 0.f;
    }
}

// ------- weight transpose + bf16 cast: Wt[l][r][h][f] = bf16(W[l][r][f][h]) -------

__global__ __launch_bounds__(256) void transpose_w(
    const float* __restrict__ rel_w0, const float* __restrict__ root_w0,
    const float* __restrict__ rel_w1, const float* __restrict__ root_w1,
    ushort_t* __restrict__ Wt) {
    int b = blockIdx.x;           // 0..17
    int layer = b / 9, r = b % 9;
    const float* src = (layer == 0) ? ((r < 8) ? (rel_w0 + r * 16384) : root_w0)
                                    : ((r < 8) ? (rel_w1 + r * 16384) : root_w1);
    __shared__ ushort_t t[128 * 130];
    for (int idx = threadIdx.x; idx < 16384; idx += 256)
        t[(idx >> 7) * 130 + (idx & 127)] = f2bf(src[idx]);
    __syncthreads();
    ushort_t* d = Wt + (size_t)b * 16384;
    for (int idx = threadIdx.x; idx < 16384; idx += 256)
        d[idx] = t[(idx & 127) * 130 + (idx >> 7)];
}

// ---------------- cast x (f32) -> compact bf16 [N,128] ----------------

__global__ void cast_x(const float* __restrict__ x, ushort_t* __restrict__ o, int total) {
    int i = (blockIdx.x * 256 + threadIdx.x) * 8;
    if (i >= total) return;
    float4 a = *(const float4*)(x + i);
    float4 b = *(const float4*)(x + i + 4);
    ushort_t t[8] = {f2bf(a.x), f2bf(a.y), f2bf(a.z), f2bf(a.w),
                     f2bf(b.x), f2bf(b.y), f2bf(b.z), f2bf(b.w)};
    *(int4v*)(o + i) = *(int4v*)t;
}

// ---------------- transform: Y[slot][node][h] = Xin @ W_slot  ----------------
// block = (node-tile 128, slot). Computes TRANSPOSED frags D[h][node]:
// A = Wt rows (m = h), B = X rows (n = node) -> C col(lane&15) = node,
// row(q*4+reg) = h -> each lane's 4 regs = 4 consecutive h = one 8B store.
// LDS 16B-chunk c of row n stored at pos c^(n&15).

__global__ __launch_bounds__(256) void transform(
    const ushort_t* __restrict__ Xin,   // [NPAD,128] bf16
    const ushort_t* __restrict__ Wt9,   // [9][128][128] bf16 (W^T per slot)
    ushort_t* __restrict__ Y,           // [9][NPAD][128] bf16
    size_t yslot) {
    __shared__ ushort_t As[128 * 128];  // W rows (h-major)
    __shared__ ushort_t Bs[128 * 128];  // X rows (node-major)
    int bi = blockIdx.x;
    int slot = bi % 9, nt = bi / 9;
    int tid = threadIdx.x;
    int wid = tid >> 6, lane = tid & 63;
    int l16 = lane & 15, q = lane >> 4;

#pragma unroll
    for (int i = 0; i < 8; ++i) {
        int L = i * 256 + tid;          // 2048 x 16B slots
        int row = L >> 4;
        int c = (L & 15) ^ (row & 15);
        gl_lds16(Wt9 + (size_t)slot * 16384 + row * 128 + c * 8,
                 (char*)As + (size_t)L * 16);
        gl_lds16(Xin + ((size_t)nt * 128 + row) * 128 + c * 8,
                 (char*)Bs + (size_t)L * 16);
    }

    f32x4 acc[2][8];
#pragma unroll
    for (int mt = 0; mt < 2; ++mt)
#pragma unroll
        for (int n8 = 0; n8 < 8; ++n8) acc[mt][n8] = (f32x4){0.f, 0.f, 0.f, 0.f};

    __syncthreads();   // drains vmcnt -> tiles visible
#pragma unroll
    for (int s = 0; s < 4; ++s) {
        int kc = (s * 4 + q);
        short8 a0 = *(const short8*)((const char*)As +
                    ((2 * wid + 0) * 16 + l16) * 256 + ((kc ^ l16) * 16));
        short8 a1 = *(const short8*)((const char*)As +
                    ((2 * wid + 1) * 16 + l16) * 256 + ((kc ^ l16) * 16));
#pragma unroll
        for (int n8 = 0; n8 < 8; ++n8) {
            short8 b = *(const short8*)((const char*)Bs +
                        (n8 * 16 + l16) * 256 + ((kc ^ l16) * 16));
            acc[0][n8] = __builtin_amdgcn_mfma_f32_16x16x32_bf16(a0, b, acc[0][n8], 0, 0, 0);
            acc[1][n8] = __builtin_amdgcn_mfma_f32_16x16x32_bf16(a1, b, acc[1][n8], 0, 0, 0);
        }
    }
    // epilogue: lane -> node = nt*128 + n8*16 + l16, h = (2*wid+mt)*16 + q*4 + reg
#pragma unroll
    for (int mt = 0; mt < 2; ++mt) {
#pragma unroll
        for (int n8 = 0; n8 < 8; ++n8) {
            int node = nt * 128 + n8 * 16 + l16;
            int h = (2 * wid + mt) * 16 + q * 4;
            ushort_t ov[4];
#pragma unroll
            for (int reg = 0; reg < 4; ++reg) ov[reg] = f2bf(acc[mt][n8][reg]);
            *(int2*)(Y + (size_t)slot * yslot + (size_t)node * FDIM + h) = *(int2*)ov;
        }
    }
}

// ---------------- aggregate: out_i = bias + Y8[i] + sum_e Y_et[src]/c ----------------
// one quarter-wave per node (16 lanes x 16B); walks per-node chain (~16 edges);
// zero LDS, 3125 blocks -> full latency overlap.

template <bool FINAL>
__global__ __launch_bounds__(256) void aggregate(
    const int* __restrict__ head, const int2* __restrict__ nxt2,
    const float* __restrict__ invc,     // [N*8]
    const ushort_t* __restrict__ Y,     // [9][NPAD][128]
    const float* __restrict__ bias,
    float* __restrict__ outF, ushort_t* __restrict__ outBf,
    size_t yslot, int N) {
    int t = blockIdx.x * 256 + threadIdx.x;
    int node = t >> 4, l16 = t & 15;
    if (node >= N) return;
    float acc[8];
#pragma unroll
    for (int k = 0; k < 8; ++k) acc[k] = 0.f;
    const float* ic = invc + node * RNUM;
    const ushort_t* Yl = Y + (size_t)l16 * 8;
    int j = head[node];
    while (j >= 0) {
        int2 e = nxt2[j];                      // one 8B line: {src, et|next}
        int et = (e.y >> 20) & 7;
        int nx = e.y & 0xFFFFF;
        float wgt = ic[et];
        int4v v = *(const int4v*)(Yl + (size_t)et * yslot + (size_t)e.x * FDIM);
        ushort_t* p = (ushort_t*)&v;
#pragma unroll
        for (int k = 0; k < 8; ++k) acc[k] += wgt * bf2f(p[k]);
        j = (nx == 0xFFFFF) ? -1 : nx;
    }
    // root + bias
    int4v vr = *(const int4v*)(Yl + (size_t)8 * yslot + (size_t)node * FDIM);
    ushort_t* pr = (ushort_t*)&vr;
    float4 b0 = *(const float4*)(bias + l16 * 8);
    float4 b1 = *(const float4*)(bias + l16 * 8 + 4);
    float bv[8] = {b0.x, b0.y, b0.z, b0.w, b1.x, b1.y, b1.z, b1.w};
    if (FINAL) {
        float o[8];
#pragma unroll
        for (int k = 0; k < 8; ++k) o[k] = acc[k] + bf2f(pr[k]) + bv[k];
        *(float4*)(outF + (size_t)node * FDIM + l16 * 8) = *(float4*)o;
        *(float4*)(outF + (size_t)node * FDIM + l16 * 8 + 4) = *(float4*)(o + 4);
    } else {
        ushort_t o[8];
#pragma unroll
        for (int k = 0; k < 8; ++k)
            o[k] = f2bf(fmaxf(acc[k] + bf2f(pr[k]) + bv[k], 0.f));
        *(int4v*)(outBf + (size_t)node * FDIM + l16 * 8) = *(int4v*)o;
    }
}

__global__ void copy_emb(const float* __restrict__ e, float* __restrict__ out, int n) {
    int i = blockIdx.x * 256 + threadIdx.x;
    if (i < n) out[i] = e[i];
}

// ---------------- launch ----------------

extern "C" void kernel_launch(void* const* d_in, const int* in_sizes, int n_in,
                              void* d_out, int out_size, void* d_ws, size_t ws_size,
                              hipStream_t stream) {
    const float* x        = (const float*)d_in[0];
    const int* edge_index = (const int*)d_in[1];
    const int* edge_type  = (const int*)d_in[2];
    const float* rel_w0   = (const float*)d_in[3];
    const float* root_w0  = (const float*)d_in[4];
    const float* bias0    = (const float*)d_in[5];
    const float* rel_w1   = (const float*)d_in[6];
    const float* root_w1  = (const float*)d_in[7];
    const float* bias1    = (const float*)d_in[8];
    const float* rel_emb  = (const float*)d_in[9];

    int N = in_sizes[0] / FDIM;   // 50000
    int E = in_sizes[1] / 2;      // 800000
    int NSEG = N * RNUM;
    const int* src = edge_index;
    const int* dst = edge_index + E;

    int nt = (N + 127) / 128;            // 391 node tiles
    int NPAD = nt * 128;                 // 50048
    size_t yslot = (size_t)NPAD * FDIM;  // elements per Y slot

    char* w = (char*)d_ws;
    auto alloc = [&](size_t bytes) -> char* {
        char* p = w;
        w += (bytes + 255) & ~(size_t)255;
        return p;
    };
    int* head      = (int*)alloc((size_t)N * 4);
    int* cnt       = (int*)alloc((size_t)NSEG * 4);
    float* invc    = (float*)alloc((size_t)NSEG * 4);
    int2* nxt2     = (int2*)alloc((size_t)E * 8);
    ushort_t* Wt   = (ushort_t*)alloc((size_t)2 * 9 * 16384 * 2);
    ushort_t* Xbf  = (ushort_t*)alloc((size_t)NPAD * FDIM * 2);
    ushort_t* hbuf = (ushort_t*)alloc((size_t)NPAD * FDIM * 2);
    ushort_t* Y    = (ushort_t*)alloc((size_t)9 * yslot * 2);   // ~115 MB
    (void)ws_size; (void)n_in; (void)out_size;

    int nb_E    = (E + 255) / 256;
    int nb_seg  = (NSEG + 255) / 256;
    int nb_cast = (N * FDIM) / (256 * 8);
    int nb_tr   = nt * 9;                    // 3519
    int nb_agg  = (N * 16 + 255) / 256;      // 3125

    hipMemsetAsync(head, 0xFF, (size_t)N * 4, stream);
    hipMemsetAsync(cnt, 0, (size_t)NSEG * 4, stream);
    link_hist<<<nb_E, 256, 0, stream>>>(src, dst, edge_type, head, cnt, nxt2, E);
    inv_cnt<<<nb_seg, 256, 0, stream>>>(cnt, invc, NSEG);
    transpose_w<<<18, 256, 0, stream>>>(rel_w0, root_w0, rel_w1, root_w1, Wt);
    cast_x<<<nb_cast, 256, 0, stream>>>(x, Xbf, N * FDIM);

    transform<<<nb_tr, 256, 0, stream>>>(Xbf, Wt, Y, yslot);
    aggregate<false><<<nb_agg, 256, 0, stream>>>(head, nxt2, invc, Y, bias0,
                                                 nullptr, hbuf, yslot, N);
    transform<<<nb_tr, 256, 0, stream>>>(hbuf, Wt + 9 * 16384, Y, yslot);
    aggregate<true><<<nb_agg, 256, 0, stream>>>(head, nxt2, invc, Y, bias1,
                                                (float*)d_out, nullptr, yslot, N);
    copy_emb<<<4, 256, 0, stream>>>(rel_emb, (float*)d_out + (size_t)N * FDIM,
                                    in_sizes[9]);
}

// Round 9
// 377.592 us; speedup vs baseline: 1.0116x; 1.0116x over previous
//
#include <hip/hip_runtime.h>

typedef unsigned short ushort_t;
typedef __attribute__((ext_vector_type(8))) short short8;
typedef __attribute__((ext_vector_type(4))) float f32x4;
typedef __attribute__((ext_vector_type(4))) int int4v;

#define RNUM 8
#define FDIM 128

__device__ __forceinline__ float bf2f(ushort_t u) {
    union { unsigned int i; float f; } x;
    x.i = ((unsigned int)u) << 16;
    return x.f;
}
__device__ __forceinline__ ushort_t f2bf(float f) {
    union { float f; unsigned int i; } x;
    x.f = f;
    unsigned int u = x.i;
    u += 0x7fffu + ((u >> 16) & 1u);   // round-to-nearest-even
    return (ushort_t)(u >> 16);
}

// async global->LDS, 16B per lane; LDS dest is wave-uniform base + lane*16
__device__ __forceinline__ void gl_lds16(const void* g, void* s) {
    __builtin_amdgcn_global_load_lds(
        (const __attribute__((address_space(1))) unsigned int*)g,
        (__attribute__((address_space(3))) unsigned int*)s, 16, 0, 0);
}

// ---------------- per-NODE linked list (no histogram) ----------------
// head[node] (memset -1) -> most recent edge; nxt2[i] = {src, et<<20|prev}.
// prev sentinel = 0xFFFFF. ONE atomic per edge; counts recovered in aggregate.

__global__ void link_kernel(const int* __restrict__ src, const int* __restrict__ dst,
                            const int* __restrict__ et, int* head,
                            int2* __restrict__ nxt2, int E) {
    int i = blockIdx.x * 256 + threadIdx.x;
    if (i < E) {
        int d = dst[i], r = et[i];
        int old = atomicExch(&head[d], i);
        int nx = (old < 0) ? 0xFFFFF : old;
        nxt2[i] = make_int2(src[i], (r << 20) | nx);
    }
}

// ------- weight transpose + bf16 cast: Wt[l][r][h][f] = bf16(W[l][r][f][h]) -------

__global__ __launch_bounds__(256) void transpose_w(
    const float* __restrict__ rel_w0, const float* __restrict__ root_w0,
    const float* __restrict__ rel_w1, const float* __restrict__ root_w1,
    ushort_t* __restrict__ Wt) {
    int b = blockIdx.x;           // 0..17
    int layer = b / 9, r = b % 9;
    const float* src = (layer == 0) ? ((r < 8) ? (rel_w0 + r * 16384) : root_w0)
                                    : ((r < 8) ? (rel_w1 + r * 16384) : root_w1);
    __shared__ ushort_t t[128 * 130];
    for (int idx = threadIdx.x; idx < 16384; idx += 256)
        t[(idx >> 7) * 130 + (idx & 127)] = f2bf(src[idx]);
    __syncthreads();
    ushort_t* d = Wt + (size_t)b * 16384;
    for (int idx = threadIdx.x; idx < 16384; idx += 256)
        d[idx] = t[(idx & 127) * 130 + (idx >> 7)];
}

// ---------------- cast x (f32) -> compact bf16 [N,128] ----------------

__global__ void cast_x(const float* __restrict__ x, ushort_t* __restrict__ o, int total) {
    int i = (blockIdx.x * 256 + threadIdx.x) * 8;
    if (i >= total) return;
    float4 a = *(const float4*)(x + i);
    float4 b = *(const float4*)(x + i + 4);
    ushort_t t[8] = {f2bf(a.x), f2bf(a.y), f2bf(a.z), f2bf(a.w),
                     f2bf(b.x), f2bf(b.y), f2bf(b.z), f2bf(b.w)};
    *(int4v*)(o + i) = *(int4v*)t;
}

// ---------------- transform: Y[slot][node][h] = Xin @ W_slot, all 9 slots/block ---------
// One block per 128-node tile: stage X-tile ONCE (kills the 9x X re-fetch of the
// per-(tile,slot) grid), loop slots staging W_r (L2-hot). Transposed frags:
// A = W rows (m=h), B = X rows (n=node) -> C col(lane&15)=node, row(q*4+reg)=h
// -> each lane's 4 acc regs = 4 consecutive h = one 8B store.
// LDS 16B-chunk c of row n stored at pos c^(n&15).

__global__ __launch_bounds__(256) void transform(
    const ushort_t* __restrict__ Xin,   // [NPAD,128] bf16
    const ushort_t* __restrict__ Wt9,   // [9][128][128] bf16 (W^T per slot)
    ushort_t* __restrict__ Y,           // [9][NPAD][128] bf16
    size_t yslot) {
    __shared__ ushort_t Ws[128 * 128];  // current W slot (rows = h)
    __shared__ ushort_t Xs[128 * 128];  // X tile (rows = node)
    int nt = blockIdx.x;
    int tid = threadIdx.x;
    int wid = tid >> 6, lane = tid & 63;
    int l16 = lane & 15, q = lane >> 4;

#pragma unroll
    for (int i = 0; i < 8; ++i) {       // stage X tile once
        int L = i * 256 + tid;
        int row = L >> 4;
        int c = (L & 15) ^ (row & 15);
        gl_lds16(Xin + ((size_t)nt * 128 + row) * 128 + c * 8,
                 (char*)Xs + (size_t)L * 16);
    }

    for (int slot = 0; slot < 9; ++slot) {
        __syncthreads();                // prev MFMA reads of Ws done (iter0: no-op)
#pragma unroll
        for (int i = 0; i < 8; ++i) {   // stage W_r (32 KB, L2-hot across blocks)
            int L = i * 256 + tid;
            int row = L >> 4;
            int c = (L & 15) ^ (row & 15);
            gl_lds16(Wt9 + (size_t)slot * 16384 + row * 128 + c * 8,
                     (char*)Ws + (size_t)L * 16);
        }
        __syncthreads();                // drains vmcnt -> tiles visible

        f32x4 acc[2][8];
#pragma unroll
        for (int mt = 0; mt < 2; ++mt)
#pragma unroll
            for (int n8 = 0; n8 < 8; ++n8) acc[mt][n8] = (f32x4){0.f, 0.f, 0.f, 0.f};
#pragma unroll
        for (int s = 0; s < 4; ++s) {
            int kc = s * 4 + q;
            short8 a0 = *(const short8*)((const char*)Ws +
                        ((2 * wid + 0) * 16 + l16) * 256 + ((kc ^ l16) * 16));
            short8 a1 = *(const short8*)((const char*)Ws +
                        ((2 * wid + 1) * 16 + l16) * 256 + ((kc ^ l16) * 16));
#pragma unroll
            for (int n8 = 0; n8 < 8; ++n8) {
                short8 b = *(const short8*)((const char*)Xs +
                            (n8 * 16 + l16) * 256 + ((kc ^ l16) * 16));
                acc[0][n8] = __builtin_amdgcn_mfma_f32_16x16x32_bf16(a0, b, acc[0][n8], 0, 0, 0);
                acc[1][n8] = __builtin_amdgcn_mfma_f32_16x16x32_bf16(a1, b, acc[1][n8], 0, 0, 0);
            }
        }
        // epilogue: node = nt*128 + n8*16 + l16, h = (2*wid+mt)*16 + q*4 + reg
#pragma unroll
        for (int mt = 0; mt < 2; ++mt) {
#pragma unroll
            for (int n8 = 0; n8 < 8; ++n8) {
                int node = nt * 128 + n8 * 16 + l16;
                int h = (2 * wid + mt) * 16 + q * 4;
                ushort_t ov[4];
#pragma unroll
                for (int reg = 0; reg < 4; ++reg) ov[reg] = f2bf(acc[mt][n8][reg]);
                *(int2*)(Y + (size_t)slot * yslot + (size_t)node * FDIM + h) = *(int2*)ov;
            }
        }
    }
}

// ---------------- aggregate: out_i = bias + Y8[i] + sum_e Y_et[src]/c ----------------
// one quarter-wave per node; pass 1 walks the chain packing per-rel counts into
// a u64 (8x8-bit), pass 2 re-walks (L2-hot) accumulating weighted rows.
// zero LDS, 3125 blocks -> full latency overlap.

template <bool FINAL>
__global__ __launch_bounds__(256) void aggregate(
    const int* __restrict__ head, const int2* __restrict__ nxt2,
    const ushort_t* __restrict__ Y,     // [9][NPAD][128]
    const float* __restrict__ bias,
    float* __restrict__ outF, ushort_t* __restrict__ outBf,
    size_t yslot, int N) {
    int t = blockIdx.x * 256 + threadIdx.x;
    int node = t >> 4, l16 = t & 15;
    if (node >= N) return;
    // pass 1: per-relation counts (broadcast loads: all 16 lanes same addr)
    unsigned long long c64 = 0;
    int j = head[node];
    while (j >= 0) {
        int y = nxt2[j].y;
        c64 += 1ULL << (((y >> 20) & 7) * 8);
        int nx = y & 0xFFFFF;
        j = (nx == 0xFFFFF) ? -1 : nx;
    }
    // pass 2: weighted accumulate
    float acc[8];
#pragma unroll
    for (int k = 0; k < 8; ++k) acc[k] = 0.f;
    const ushort_t* Yl = Y + (size_t)l16 * 8;
    j = head[node];
    while (j >= 0) {
        int2 e = nxt2[j];                      // L2-hot from pass 1
        int et = (e.y >> 20) & 7;
        int nx = e.y & 0xFFFFF;
        int c = (int)((c64 >> (et * 8)) & 255);
        float wgt = 1.0f / (float)c;           // exact; c >= 1 here
        int4v v = *(const int4v*)(Yl + (size_t)et * yslot + (size_t)e.x * FDIM);
        ushort_t* p = (ushort_t*)&v;
#pragma unroll
        for (int k = 0; k < 8; ++k) acc[k] += wgt * bf2f(p[k]);
        j = (nx == 0xFFFFF) ? -1 : nx;
    }
    // root + bias
    int4v vr = *(const int4v*)(Yl + (size_t)8 * yslot + (size_t)node * FDIM);
    ushort_t* pr = (ushort_t*)&vr;
    float4 b0 = *(const float4*)(bias + l16 * 8);
    float4 b1 = *(const float4*)(bias + l16 * 8 + 4);
    float bv[8] = {b0.x, b0.y, b0.z, b0.w, b1.x, b1.y, b1.z, b1.w};
    if (FINAL) {
        float o[8];
#pragma unroll
        for (int k = 0; k < 8; ++k) o[k] = acc[k] + bf2f(pr[k]) + bv[k];
        *(float4*)(outF + (size_t)node * FDIM + l16 * 8) = *(float4*)o;
        *(float4*)(outF + (size_t)node * FDIM + l16 * 8 + 4) = *(float4*)(o + 4);
    } else {
        ushort_t o[8];
#pragma unroll
        for (int k = 0; k < 8; ++k)
            o[k] = f2bf(fmaxf(acc[k] + bf2f(pr[k]) + bv[k], 0.f));
        *(int4v*)(outBf + (size_t)node * FDIM + l16 * 8) = *(int4v*)o;
    }
}

__global__ void copy_emb(const float* __restrict__ e, float* __restrict__ out, int n) {
    int i = blockIdx.x * 256 + threadIdx.x;
    if (i < n) out[i] = e[i];
}

// ---------------- launch ----------------

extern "C" void kernel_launch(void* const* d_in, const int* in_sizes, int n_in,
                              void* d_out, int out_size, void* d_ws, size_t ws_size,
                              hipStream_t stream) {
    const float* x        = (const float*)d_in[0];
    const int* edge_index = (const int*)d_in[1];
    const int* edge_type  = (const int*)d_in[2];
    const float* rel_w0   = (const float*)d_in[3];
    const float* root_w0  = (const float*)d_in[4];
    const float* bias0    = (const float*)d_in[5];
    const float* rel_w1   = (const float*)d_in[6];
    const float* root_w1  = (const float*)d_in[7];
    const float* bias1    = (const float*)d_in[8];
    const float* rel_emb  = (const float*)d_in[9];

    int N = in_sizes[0] / FDIM;   // 50000
    int E = in_sizes[1] / 2;      // 800000
    const int* src = edge_index;
    const int* dst = edge_index + E;

    int nt = (N + 127) / 128;            // 391 node tiles
    int NPAD = nt * 128;                 // 50048
    size_t yslot = (size_t)NPAD * FDIM;  // elements per Y slot

    char* w = (char*)d_ws;
    auto alloc = [&](size_t bytes) -> char* {
        char* p = w;
        w += (bytes + 255) & ~(size_t)255;
        return p;
    };
    int* head      = (int*)alloc((size_t)N * 4);
    int2* nxt2     = (int2*)alloc((size_t)E * 8);
    ushort_t* Wt   = (ushort_t*)alloc((size_t)2 * 9 * 16384 * 2);
    ushort_t* Xbf  = (ushort_t*)alloc((size_t)NPAD * FDIM * 2);
    ushort_t* hbuf = (ushort_t*)alloc((size_t)NPAD * FDIM * 2);
    ushort_t* Y    = (ushort_t*)alloc((size_t)9 * yslot * 2);   // ~115 MB
    (void)ws_size; (void)n_in; (void)out_size;

    int nb_E    = (E + 255) / 256;
    int nb_cast = (N * FDIM) / (256 * 8);
    int nb_agg  = (N * 16 + 255) / 256;      // 3125

    hipMemsetAsync(head, 0xFF, (size_t)N * 4, stream);
    link_kernel<<<nb_E, 256, 0, stream>>>(src, dst, edge_type, head, nxt2, E);
    transpose_w<<<18, 256, 0, stream>>>(rel_w0, root_w0, rel_w1, root_w1, Wt);
    cast_x<<<nb_cast, 256, 0, stream>>>(x, Xbf, N * FDIM);

    transform<<<nt, 256, 0, stream>>>(Xbf, Wt, Y, yslot);
    aggregate<false><<<nb_agg, 256, 0, stream>>>(head, nxt2, Y, bias0,
                                                 nullptr, hbuf, yslot, N);
    transform<<<nt, 256, 0, stream>>>(hbuf, Wt + 9 * 16384, Y, yslot);
    aggregate<true><<<nb_agg, 256, 0, stream>>>(head, nxt2, Y, bias1,
                                                (float*)d_out, nullptr, yslot, N);
    copy_emb<<<4, 256, 0, stream>>>(rel_emb, (float*)d_out + (size_t)N * FDIM,
                                    in_sizes[9]);
}